// Round 1
// baseline (163.710 us; speedup 1.0000x reference)
//
#include <hip/hip_runtime.h>

// Problem constants (from reference setup_inputs):
//   features [B=32, C=2048, T=8, H=7, W=7] f32, W [C=2048, K=400] f32,
//   labels [B] int, unchanged_mask [B] int.
// z_grads[b,c,:,:,:] = W[c, labels[b]] / 392  (grad of avg-pool+linear pick).
// quantile(0.77, N=802816, linear) -> exactly the channel of sorted rank 1576.
#define B_  32
#define C_  2048
#define K_  400
#define POOL_N 392.0f
#define RANK_ 1576   // floor(0.77*(802816-1)) // 392 == ceil idx // 392 == 1576

__global__ __launch_bounds__(1024) void thr_factor_kernel(
    const float* __restrict__ Wm, const int* __restrict__ labels,
    const int* __restrict__ unch, float* __restrict__ factor) {
  const int b = blockIdx.x;
  const int tid = threadIdx.x;
  __shared__ float z[C_];
  __shared__ float s_thr;

  const int l = labels[b];
  // Stage the label's W column as z = W/392 (same fp32 division as autodiff VJP).
  for (int i = tid; i < C_; i += 1024) {
    z[i] = Wm[i * K_ + l] / POOL_N;
  }
  __syncthreads();

  // Rank-select sorted[RANK_] by counting (O(C^2) across 1024 threads,
  // LDS broadcast reads in the inner loop -> conflict-free).
  const float z0 = z[tid];
  const float z1 = z[tid + 1024];
  int cl0 = 0, ce0 = 0, cl1 = 0, ce1 = 0;
  for (int j = 0; j < C_; ++j) {
    const float v = z[j];
    cl0 += (v < z0); ce0 += (v == z0);
    cl1 += (v < z1); ce1 += (v == z1);
  }
  // Exactly one distinct value satisfies cl <= RANK < cl+ce; ties write same bits.
  if (cl0 <= RANK_ && RANK_ < cl0 + ce0) s_thr = z0;
  if (cl1 <= RANK_ && RANK_ < cl1 + ce1) s_thr = z1;
  __syncthreads();

  const float thr = s_thr;
  const bool unchanged = (unch[b] != 0);
  const float scale = (float)(1.0 / 0.77);  // rounded to f32, matches jnp promotion
  for (int i = tid; i < C_; i += 1024) {
    // zero_mask uses strict '>': the rank-1576 element itself is KEPT.
    const float f = unchanged ? 1.0f : ((z[i] > thr) ? 0.0f : scale);
    factor[b * C_ + i] = f;
  }
}

__global__ __launch_bounds__(256) void apply_kernel(
    const float* __restrict__ in, const float* __restrict__ factor,
    float* __restrict__ out, int nvec) {
  const int stride = gridDim.x * 256;
  for (int v = blockIdx.x * 256 + threadIdx.x; v < nvec; v += stride) {
    // 392 floats per (b,c) = 98 float4s: each vec4 lies within one (b,c).
    const float s = factor[v / 98];
    float4 x = reinterpret_cast<const float4*>(in)[v];
    x.x *= s; x.y *= s; x.z *= s; x.w *= s;
    reinterpret_cast<float4*>(out)[v] = x;
  }
}

extern "C" void kernel_launch(void* const* d_in, const int* in_sizes, int n_in,
                              void* d_out, int out_size, void* d_ws, size_t ws_size,
                              hipStream_t stream) {
  const float* features = (const float*)d_in[0];
  const float* Wm       = (const float*)d_in[1];
  const int*   labels   = (const int*)d_in[2];
  const int*   unch     = (const int*)d_in[3];
  float* out = (float*)d_out;
  float* factor = (float*)d_ws;  // B_*C_ floats = 256 KiB scratch

  thr_factor_kernel<<<B_, 1024, 0, stream>>>(Wm, labels, unch, factor);

  const int nvec = in_sizes[0] / 4;  // 6,422,528 float4s
  apply_kernel<<<2048, 256, 0, stream>>>(features, factor, out, nvec);
}

// Round 4
// 66.237 us; speedup vs baseline: 2.4716x; 2.4716x over previous
//
#include <hip/hip_runtime.h>

// features [B=32, C=2048, T=8, H=7, W=7] f32, W [C=2048, K=400] f32,
// labels [B] int, unchanged_mask [B] int.
// z_grads[b,c,:,:,:] = W[c, labels[b]] / 392  (grad of avgpool+linear pick).
// quantile(0.77, N=802816, linear): idx 618167.55 -> both floor/ceil fall in
// the 392-block of sorted channel rank 1576 -> thr[b] = kth(W[:,l_b]/392, 1576).
#define B_  32
#define C_  2048
#define K_  400
#define POOL_N 392.0f
#define RANK_ 1576

// ---- Kernel A: per-batch threshold via distributed rank-count -------------
// 32 b x 8 i-slices = 256 blocks; each thread owns one channel i and counts
// (less, equal) against all 2048 z via LDS float4 broadcast reads.
__global__ __launch_bounds__(256) void thr_kernel(
    const float* __restrict__ Wm, const int* __restrict__ labels,
    float* __restrict__ thr_out) {
  const int b   = blockIdx.x >> 3;
  const int s   = blockIdx.x & 7;
  const int tid = threadIdx.x;
  __shared__ __align__(16) float z[C_];

  const int l = labels[b];
  for (int i = tid; i < C_; i += 256) z[i] = Wm[i * K_ + l] / POOL_N;
  __syncthreads();

  const float zi = z[s * 256 + tid];
  int cl = 0, ce = 0;
  #pragma unroll 4
  for (int j = 0; j < C_; j += 4) {
    const float4 v = *reinterpret_cast<const float4*>(&z[j]);  // broadcast
    cl += (v.x <  zi) + (v.y <  zi) + (v.z <  zi) + (v.w <  zi);
    ce += (v.x == zi) + (v.y == zi) + (v.z == zi) + (v.w == zi);
  }
  // Exactly one distinct value satisfies; tied threads write identical bits.
  if (cl <= RANK_ && RANK_ < cl + ce) thr_out[b] = zi;
}

// ---- Kernel B: streaming apply with inline factor -------------------------
__global__ __launch_bounds__(256) void apply_kernel(
    const float* __restrict__ in, const float* __restrict__ Wm,
    const int* __restrict__ labels, const int* __restrict__ unch,
    const float* __restrict__ thr, float* __restrict__ out, int nvec) {
  const int stride = gridDim.x * 256;
  const float scale = (float)(1.0 / 0.77);
  for (int v = blockIdx.x * 256 + threadIdx.x; v < nvec; v += stride) {
    // 392 floats per (b,c) = 98 float4s: each vec4 lies within one (b,c).
    const int bc = v / 98;            // magic-mul, exact
    const int b  = bc >> 11;          // C_ = 2048
    const int c  = bc & (C_ - 1);
    float f;
    if (unch[b] != 0) {
      f = 1.0f;
    } else {
      const float zz = Wm[c * K_ + labels[b]] / POOL_N;  // L2-hot (32 cols)
      f = (zz > thr[b]) ? 0.0f : scale;                  // strict '>': rank elem kept
    }
    float4 x = reinterpret_cast<const float4*>(in)[v];
    x.x *= f; x.y *= f; x.z *= f; x.w *= f;
    reinterpret_cast<float4*>(out)[v] = x;
  }
}

extern "C" void kernel_launch(void* const* d_in, const int* in_sizes, int n_in,
                              void* d_out, int out_size, void* d_ws, size_t ws_size,
                              hipStream_t stream) {
  const float* features = (const float*)d_in[0];
  const float* Wm       = (const float*)d_in[1];
  const int*   labels   = (const int*)d_in[2];
  const int*   unch     = (const int*)d_in[3];
  float* out = (float*)d_out;
  float* thr = (float*)d_ws;  // 32 floats

  thr_kernel<<<B_ * 8, 256, 0, stream>>>(Wm, labels, thr);

  const int nvec = in_sizes[0] / 4;  // 6,422,528 float4s
  apply_kernel<<<2048, 256, 0, stream>>>(features, Wm, labels, unch, thr, out, nvec);
}